// Round 2
// baseline (1132.373 us; speedup 1.0000x reference)
//
#include <hip/hip_runtime.h>
#include <cstdio>

using u16 = unsigned short;
using u32 = unsigned int;

typedef __attribute__((ext_vector_type(8))) u16    u16x8;
typedef __attribute__((ext_vector_type(8))) __bf16 bf16x8;
typedef __attribute__((ext_vector_type(4))) float  f32x4;

constexpr int NN = 50000;   // nodes
constexpr int NE = 250000;  // edges
constexpr int EU_BLOCKS = 2048;

// ---------------- ws layout (bytes) ----------------
constexpr size_t OFF_NFA  = 0;                                  // bf16 [NN,128]  nf_dense @ Wa
constexpr size_t OFF_NFB  = OFF_NFA  + (size_t)NN*128*2;        // bf16 [NN,128]  nf_dense @ Wb
constexpr size_t OFF_NFN1 = OFF_NFB  + (size_t)NN*128*2;        // bf16 [NN,128]  nf_dense @ Wn1
constexpr size_t OFF_EFC  = OFF_NFN1 + (size_t)NN*128*2;        // bf16 [NE,128]  ef_dense @ Wc
constexpr size_t OFF_NACC = OFF_EFC  + (size_t)NE*128*2;        // f32  [NN,128]
constexpr size_t OFF_NCNT = OFF_NACC + (size_t)NN*128*4;        // u32  [NN] (padded to 200192B)
constexpr size_t OFF_EMS  = OFF_NCNT + 200192;                  // f32  [EU_BLOCKS,2048]
constexpr size_t OFF_EMCS = OFF_EMS  + (size_t)EU_BLOCKS*2048*4;// u32  [EU_BLOCKS,16]
constexpr size_t OFF_EMA  = OFF_EMCS + (size_t)EU_BLOCKS*16*4;  // f32  [2048]
constexpr size_t OFF_EMC  = OFF_EMA  + 8192;                    // f32  [16] (padded)
constexpr size_t OFF_NMA  = OFF_EMC  + 256;                     // f32  [2048]
constexpr size_t OFF_NMC  = OFF_NMA  + 8192;                    // u32  [16] (padded)
constexpr size_t OFF_GFP  = OFF_NMC  + 256;                     // f32  [16,128] gf_pre
constexpr size_t OFF_GFD  = OFF_GFP  + 8192;                    // f32  gf_pre@Wd+emb
constexpr size_t OFF_GFN3 = OFF_GFD  + 8192;                    // f32  gf_pre@Wn3+nmb
constexpr size_t OFF_PACK = OFF_GFN3 + 8192;                    // bf16 packed weights 212992
constexpr size_t WS_NEED  = OFF_PACK + (size_t)212992*2;

// ---------------- helpers ----------------
static __device__ __forceinline__ float b2f(u16 u) {
    union { u32 u; float f; } x; x.u = ((u32)u) << 16; return x.f;
}
static __device__ __forceinline__ u16 f2bf(float f) {
    union { float f; u32 u; } x; x.f = f;
    u32 r = x.u + 0x7fffu + ((x.u >> 16) & 1u);
    return (u16)(r >> 16);
}
static __device__ __forceinline__ float sp2(float x) {
    // softplus(x) - ln2, numerically stable
    return fmaxf(x, 0.f) + __logf(1.f + __expf(-fabsf(x))) - 0.6931471805599453f;
}
static __device__ __forceinline__ bf16x8 ldbf8(const u16* p) {
    return __builtin_bit_cast(bf16x8, *(const u16x8*)p);
}

// ---------------- weight pre-swizzle (fp32 -> bf16 B-fragment order) ----------------
// packed[((nt*KC + kc)*64 + lane)*8 + j] = W[(rowOff + kc*32 + (lane>>4)*8 + j)*Nsrc + nt*16 + (lane&15)]
__global__ __launch_bounds__(256) void pack_kernel(
    const float* __restrict__ eW1, const float* __restrict__ eW2,
    const float* __restrict__ nW1, const float* __restrict__ nW2,
    const float* __restrict__ emW, const float* __restrict__ nmW,
    u16* __restrict__ dst)
{
    int gid = blockIdx.x * 256 + threadIdx.x;
    if (gid >= 212992) return;
    const float* src; int rowOff, Nsrc, KC, local;
    if      (gid <  32768) { src=eW1; rowOff=0;   Nsrc=256; KC=4; local=gid; }
    else if (gid <  65536) { src=eW2; rowOff=0;   Nsrc=128; KC=8; local=gid-32768; }
    else if (gid <  98304) { src=nW1; rowOff=0;   Nsrc=256; KC=4; local=gid-65536; }
    else if (gid < 131072) { src=nW2; rowOff=0;   Nsrc=128; KC=8; local=gid-98304; }
    else if (gid < 147456) { src=emW; rowOff=0;   Nsrc=128; KC=4; local=gid-131072; } // Wa
    else if (gid < 163840) { src=emW; rowOff=128; Nsrc=128; KC=4; local=gid-147456; } // Wb
    else if (gid < 180224) { src=emW; rowOff=256; Nsrc=128; KC=4; local=gid-163840; } // Wc
    else if (gid < 196608) { src=nmW; rowOff=0;   Nsrc=128; KC=4; local=gid-180224; } // Wn1
    else                   { src=nmW; rowOff=128; Nsrc=128; KC=4; local=gid-196608; } // Wn2
    int j    = local & 7;
    int lane = (local >> 3) & 63;
    int t    = local >> 9;
    int kc   = t & (KC - 1);
    int nt   = t >> (KC == 8 ? 3 : 2);
    int k = kc * 32 + ((lane >> 4) << 3) + j;
    int n = nt * 16 + (lane & 15);
    dst[gid] = f2bf(src[(size_t)(rowOff + k) * Nsrc + n]);
}

// ---------------- fused MLP (dense pre-block + stage-3 projections), MFMA ----------------
template<int NPROJ>
__global__ __launch_bounds__(256) void mlp_kernel(
    const float* __restrict__ in, int M,
    const u16* __restrict__ W1p, const float* __restrict__ b1,
    const u16* __restrict__ W2p, const float* __restrict__ b2,
    const u16* __restrict__ P0, const u16* __restrict__ P1, const u16* __restrict__ P2,
    u16* __restrict__ O0, u16* __restrict__ O1, u16* __restrict__ O2)
{
    __shared__ u16 sA[64 * 136];   // input tile, later h2 tile (pitch 136 => +4 banks/row)
    __shared__ u16 sH[64 * 264];   // h1 tile (pitch 264)
    int tid  = threadIdx.x;
    int base = blockIdx.x * 64;
    // stage input tile [64,128] fp32 -> bf16
    {
        int r = tid >> 2, p = tid & 3;
        int row = base + r;
        u16* d = sA + r * 136 + p * 32;
        if (row < M) {
            const float* s = in + (size_t)row * 128 + p * 32;
            #pragma unroll
            for (int i = 0; i < 4; i++) {
                f32x4 f0 = *(const f32x4*)(s + i * 8);
                f32x4 f1 = *(const f32x4*)(s + i * 8 + 4);
                u16x8 v;
                v[0]=f2bf(f0[0]); v[1]=f2bf(f0[1]); v[2]=f2bf(f0[2]); v[3]=f2bf(f0[3]);
                v[4]=f2bf(f1[0]); v[5]=f2bf(f1[1]); v[6]=f2bf(f1[2]); v[7]=f2bf(f1[3]);
                *(u16x8*)(d + i * 8) = v;
            }
        } else {
            u16x8 z = {0,0,0,0,0,0,0,0};
            #pragma unroll
            for (int i = 0; i < 4; i++) *(u16x8*)(d + i * 8) = z;
        }
    }
    __syncthreads();
    int lane = tid & 63, w = tid >> 6, q = lane >> 4, lm = lane & 15;
    // ---- stage 1: h1 = sp2(in @ W1 + b1)  [16 rows/wave, 256 cols]
    {
        bf16x8 a[4];
        const u16* ar = sA + (w * 16 + lm) * 136;
        #pragma unroll
        for (int kc = 0; kc < 4; kc++) a[kc] = ldbf8(ar + kc * 32 + q * 8);
        for (int nt = 0; nt < 16; nt++) {
            f32x4 acc = {0.f, 0.f, 0.f, 0.f};
            const u16* bp = W1p + nt * 2048 + lane * 8;
            #pragma unroll
            for (int kc = 0; kc < 4; kc++)
                acc = __builtin_amdgcn_mfma_f32_16x16x32_bf16(a[kc], ldbf8(bp + kc * 512), acc, 0, 0, 0);
            int col = nt * 16 + lm;
            float bias = b1[col];
            #pragma unroll
            for (int r = 0; r < 4; r++)
                sH[(w * 16 + q * 4 + r) * 264 + col] = f2bf(sp2(acc[r] + bias));
        }
    }
    // ---- stage 2: h2 = sp2(h1 @ W2 + b2)  (wave-private rows; same-wave LDS is in-order)
    {
        bf16x8 a[8];
        const u16* ar = sH + (w * 16 + lm) * 264;
        #pragma unroll
        for (int kc = 0; kc < 8; kc++) a[kc] = ldbf8(ar + kc * 32 + q * 8);
        for (int nt = 0; nt < 8; nt++) {
            f32x4 acc = {0.f, 0.f, 0.f, 0.f};
            const u16* bp = W2p + nt * 4096 + lane * 8;
            #pragma unroll
            for (int kc = 0; kc < 8; kc++)
                acc = __builtin_amdgcn_mfma_f32_16x16x32_bf16(a[kc], ldbf8(bp + kc * 512), acc, 0, 0, 0);
            int col = nt * 16 + lm;
            float bias = b2[col];
            #pragma unroll
            for (int r = 0; r < 4; r++)
                sA[(w * 16 + q * 4 + r) * 136 + col] = f2bf(sp2(acc[r] + bias));
        }
    }
    // ---- stage 3: projections h2 @ P[p] -> O[p] (bf16 out, no bias)
    {
        bf16x8 a[4];
        const u16* ar = sA + (w * 16 + lm) * 136;
        #pragma unroll
        for (int kc = 0; kc < 4; kc++) a[kc] = ldbf8(ar + kc * 32 + q * 8);
        const u16* Ps[3] = {P0, P1, P2};
        u16*       Os[3] = {O0, O1, O2};
        #pragma unroll
        for (int p = 0; p < NPROJ; p++) {
            for (int nt = 0; nt < 8; nt++) {
                f32x4 acc = {0.f, 0.f, 0.f, 0.f};
                const u16* bp = Ps[p] + nt * 2048 + lane * 8;
                #pragma unroll
                for (int kc = 0; kc < 4; kc++)
                    acc = __builtin_amdgcn_mfma_f32_16x16x32_bf16(a[kc], ldbf8(bp + kc * 512), acc, 0, 0, 0);
                int col = nt * 16 + lm;
                #pragma unroll
                for (int r = 0; r < 4; r++) {
                    int row = base + w * 16 + q * 4 + r;
                    if (row < M) Os[p][(size_t)row * 128 + col] = f2bf(acc[r]);
                }
            }
        }
    }
}

// ---------------- global-features dense pre-block (tiny, 1 block, fp32) ----------------
__global__ __launch_bounds__(256) void gdense_kernel(
    const float* __restrict__ gf0, const float* __restrict__ gW1, const float* __restrict__ gb1,
    const float* __restrict__ gW2, const float* __restrict__ gb2,
    const float* __restrict__ emW, const float* __restrict__ emb,
    const float* __restrict__ nmW, const float* __restrict__ nmb,
    float* __restrict__ gf_pre, float* __restrict__ gfd, float* __restrict__ gfn3b)
{
    __shared__ float s_in[16 * 128];
    __shared__ float s_h1[16 * 256];
    __shared__ float s_h2[16 * 128];
    int tid = threadIdx.x;
    for (int i = tid; i < 2048; i += 256) s_in[i] = gf0[i];
    __syncthreads();
    for (int o = tid; o < 4096; o += 256) {
        int row = o >> 8, col = o & 255;
        float acc = gb1[col];
        for (int k = 0; k < 128; k++) acc += s_in[row * 128 + k] * gW1[k * 256 + col];
        s_h1[o] = sp2(acc);
    }
    __syncthreads();
    for (int o = tid; o < 2048; o += 256) {
        int row = o >> 7, col = o & 127;
        float acc = gb2[col];
        for (int k = 0; k < 256; k++) acc += s_h1[row * 256 + k] * gW2[k * 128 + col];
        float v = sp2(acc);
        s_h2[o] = v; gf_pre[o] = v;
    }
    __syncthreads();
    for (int o = tid; o < 2048; o += 256) {
        int row = o >> 7, col = o & 127;
        float a1 = emb[col], a2 = nmb[col];
        for (int k = 0; k < 128; k++) {
            float h = s_h2[row * 128 + k];
            a1 += h * emW[(size_t)(384 + k) * 128 + col];
            a2 += h * nmW[(size_t)(256 + k) * 128 + col];
        }
        gfd[o] = a1; gfn3b[o] = a2;
    }
}

// ---------------- edge update + scatters ----------------
__global__ __launch_bounds__(256) void edge_update_kernel(
    const int* __restrict__ ei, const int* __restrict__ batch,
    const float* __restrict__ ef0, const u16* __restrict__ nfa, const u16* __restrict__ nfb,
    const u16* __restrict__ efc, const float* __restrict__ gfd,
    float* __restrict__ ef_out, float* __restrict__ node_acc, u32* __restrict__ node_cnt,
    float* __restrict__ em_scratch, u32* __restrict__ emcnt_scratch)
{
    __shared__ float s_em[2048];
    __shared__ u32 s_cnt[16];
    int tid = threadIdx.x;
    for (int i = tid; i < 2048; i += 256) s_em[i] = 0.f;
    if (tid < 16) s_cnt[tid] = 0;
    __syncthreads();
    int slot = tid >> 7, j = tid & 127;
    int e0 = (int)(((long)blockIdx.x * NE) / EU_BLOCKS);
    int e1 = (int)(((long)(blockIdx.x + 1) * NE) / EU_BLOCKS);
    for (int e = e0 + slot; e < e1; e += 2) {
        int s = ei[e], d = ei[NE + e];
        int bf = batch[s], bb = batch[d];
        float ec = b2f(efc[(size_t)e * 128 + j]);
        float f  = b2f(nfa[(size_t)s * 128 + j]) + b2f(nfb[(size_t)d * 128 + j]) + ec + gfd[bf * 128 + j];
        float g_ = b2f(nfa[(size_t)d * 128 + j]) + b2f(nfb[(size_t)s * 128 + j]) + ec + gfd[bb * 128 + j];
        ef_out[(size_t)e * 128 + j] = 0.5f * (f + g_) + ef0[(size_t)e * 128 + j];
        unsafeAtomicAdd(&node_acc[(size_t)d * 128 + j], f);
        unsafeAtomicAdd(&node_acc[(size_t)s * 128 + j], g_);
        atomicAdd(&s_em[bf * 128 + j], f);
        atomicAdd(&s_em[bb * 128 + j], g_);
        if (j == 0) {
            atomicAdd(&node_cnt[d], 1u); atomicAdd(&node_cnt[s], 1u);
            atomicAdd(&s_cnt[bf], 1u);   atomicAdd(&s_cnt[bb], 1u);
        }
    }
    __syncthreads();
    float* dst = em_scratch + (size_t)blockIdx.x * 2048;
    for (int i = tid; i < 2048; i += 256) dst[i] = s_em[i];
    if (tid < 16) emcnt_scratch[blockIdx.x * 16 + tid] = s_cnt[tid];
}

__global__ __launch_bounds__(256) void em_reduce_kernel(
    const float* __restrict__ ems, const u32* __restrict__ emcs,
    float* __restrict__ em, float* __restrict__ em_cnt)
{
    int idx = blockIdx.x * 256 + threadIdx.x;  // 0..2047
    float s = 0.f;
    for (int b = 0; b < EU_BLOCKS; b++) s += ems[(size_t)b * 2048 + idx];
    em[idx] = s;
    if (idx < 16) {
        u32 c = 0;
        for (int b = 0; b < EU_BLOCKS; b++) c += emcs[b * 16 + idx];
        em_cnt[idx] = (float)c;
    }
}

// ---------------- node update (efm @ Wn2 via MFMA) ----------------
__global__ __launch_bounds__(256) void node_update_kernel(
    const float* __restrict__ nf0, const u16* __restrict__ nfn1,
    const float* __restrict__ node_acc, const u32* __restrict__ node_cnt,
    const u16* __restrict__ Wn2p, const float* __restrict__ gfn3b, const int* __restrict__ batch,
    float* __restrict__ nf_out, float* __restrict__ nm_acc, u32* __restrict__ nm_cnt)
{
    __shared__ u16 sE[64 * 136];
    __shared__ float s_nm[2048];
    __shared__ u32 s_ncnt[16];
    int tid = threadIdx.x;
    for (int i = tid; i < 2048; i += 256) s_nm[i] = 0.f;
    if (tid < 16) s_ncnt[tid] = 0;
    __syncthreads();
    int base = blockIdx.x * 64;
    {
        int r = tid >> 2, p = tid & 3;
        int n = base + r;
        u16* d = sE + r * 136 + p * 32;
        if (n < NN) {
            float inv = 1.f / fmaxf((float)node_cnt[n], 1.f);
            const float* pa = node_acc + (size_t)n * 128 + p * 32;
            #pragma unroll
            for (int i = 0; i < 32; i++) d[i] = f2bf(pa[i] * inv);
            if (p == 0) atomicAdd(&s_ncnt[batch[n]], 1u);
        } else {
            for (int i = 0; i < 32; i++) d[i] = 0;
        }
    }
    __syncthreads();
    int lane = tid & 63, w = tid >> 6, q = lane >> 4, lm = lane & 15;
    int rows[4]; bool ok[4]; int gg[4];
    #pragma unroll
    for (int r = 0; r < 4; r++) {
        rows[r] = base + w * 16 + q * 4 + r;
        ok[r] = rows[r] < NN;
        gg[r] = ok[r] ? batch[rows[r]] : 0;
    }
    bf16x8 a[4];
    const u16* ar = sE + (w * 16 + lm) * 136;
    #pragma unroll
    for (int kc = 0; kc < 4; kc++) a[kc] = ldbf8(ar + kc * 32 + q * 8);
    for (int nt = 0; nt < 8; nt++) {
        f32x4 acc = {0.f, 0.f, 0.f, 0.f};
        const u16* bp = Wn2p + nt * 2048 + lane * 8;
        #pragma unroll
        for (int kc = 0; kc < 4; kc++)
            acc = __builtin_amdgcn_mfma_f32_16x16x32_bf16(a[kc], ldbf8(bp + kc * 512), acc, 0, 0, 0);
        int col = nt * 16 + lm;
        #pragma unroll
        for (int r = 0; r < 4; r++) {
            if (ok[r]) {
                size_t idx = (size_t)rows[r] * 128 + col;
                float upd = acc[r] + b2f(nfn1[idx]) + gfn3b[gg[r] * 128 + col];
                nf_out[idx] = upd + nf0[idx];
                atomicAdd(&s_nm[gg[r] * 128 + col], upd);
            }
        }
    }
    __syncthreads();
    for (int g = 0; g < 16; g++) {
        u32 c = s_ncnt[g];
        if (c) {
            if (tid < 128) unsafeAtomicAdd(&nm_acc[g * 128 + tid], s_nm[g * 128 + tid]);
            if (tid == 0) atomicAdd(&nm_cnt[g], c);
        }
    }
}

// ---------------- global update (tiny, 1 block, fp32) ----------------
__global__ __launch_bounds__(256) void global_update_kernel(
    const float* __restrict__ gf0, const float* __restrict__ gf_pre,
    const float* __restrict__ em, const float* __restrict__ em_cnt,
    const float* __restrict__ nm_acc, const u32* __restrict__ nm_cnt,
    const float* __restrict__ gmW, const float* __restrict__ gmb,
    float* __restrict__ gf_out)
{
    __shared__ float s_cat[16 * 384];
    int tid = threadIdx.x;
    for (int i = tid; i < 2048; i += 256) {
        int g = i >> 7, c = i & 127;
        s_cat[g * 384 + c]       = em[i] / fmaxf(em_cnt[g], 1.f);
        s_cat[g * 384 + 128 + c] = nm_acc[i] / fmaxf((float)nm_cnt[g], 1.f);
        s_cat[g * 384 + 256 + c] = gf_pre[i];
    }
    __syncthreads();
    for (int o = tid; o < 2048; o += 256) {
        int g = o >> 7, c = o & 127;
        float acc = gmb[c];
        for (int k = 0; k < 384; k++) acc += s_cat[g * 384 + k] * gmW[k * 128 + c];
        gf_out[o] = acc + gf0[o];
    }
}

// ---------------- launcher ----------------
extern "C" void kernel_launch(void* const* d_in, const int* in_sizes, int n_in,
                              void* d_out, int out_size, void* d_ws, size_t ws_size,
                              hipStream_t stream) {
    const float* nf0 = (const float*)d_in[0];
    const int*   ei  = (const int*)d_in[1];
    const float* ef0 = (const float*)d_in[2];
    const float* gf0 = (const float*)d_in[3];
    const int* batch = (const int*)d_in[4];
    const float *eW1 = (const float*)d_in[5],  *eb1 = (const float*)d_in[6];
    const float *eW2 = (const float*)d_in[7],  *eb2 = (const float*)d_in[8];
    const float *nW1 = (const float*)d_in[9],  *nb1 = (const float*)d_in[10];
    const float *nW2 = (const float*)d_in[11], *nb2 = (const float*)d_in[12];
    const float *gW1 = (const float*)d_in[13], *gb1 = (const float*)d_in[14];
    const float *gW2 = (const float*)d_in[15], *gb2 = (const float*)d_in[16];
    const float *emW = (const float*)d_in[17], *emb = (const float*)d_in[18];
    const float *nmW = (const float*)d_in[19], *nmb = (const float*)d_in[20];
    const float *gmW = (const float*)d_in[21], *gmb = (const float*)d_in[22];

    if (ws_size < WS_NEED) {
        fprintf(stderr, "kernel_launch: ws too small: %zu < %zu\n", ws_size, WS_NEED);
        return;
    }
    char* ws = (char*)d_ws;
    u16* nfa  = (u16*)(ws + OFF_NFA);
    u16* nfb  = (u16*)(ws + OFF_NFB);
    u16* nfn1 = (u16*)(ws + OFF_NFN1);
    u16* efc  = (u16*)(ws + OFF_EFC);
    u16* pk   = (u16*)(ws + OFF_PACK);

    float* nf_out = (float*)d_out;
    float* ef_out = nf_out + (size_t)NN * 128;
    float* gf_out = ef_out + (size_t)NE * 128;

    hipMemsetAsync(ws + OFF_NACC, 0, (size_t)NN * 128 * 4 + 200192, stream);
    hipMemsetAsync(ws + OFF_NMA, 0, 8192 + 256, stream);

    pack_kernel<<<832, 256, 0, stream>>>(eW1, eW2, nW1, nW2, emW, nmW, pk);
    gdense_kernel<<<1, 256, 0, stream>>>(gf0, gW1, gb1, gW2, gb2, emW, emb, nmW, nmb,
                                         (float*)(ws + OFF_GFP), (float*)(ws + OFF_GFD),
                                         (float*)(ws + OFF_GFN3));
    mlp_kernel<3><<<(NN + 63) / 64, 256, 0, stream>>>(
        nf0, NN, pk + 65536, nb1, pk + 98304, nb2,
        pk + 131072, pk + 147456, pk + 180224, nfa, nfb, nfn1);
    mlp_kernel<1><<<(NE + 63) / 64, 256, 0, stream>>>(
        ef0, NE, pk + 0, eb1, pk + 32768, eb2,
        pk + 163840, nullptr, nullptr, efc, nullptr, nullptr);
    edge_update_kernel<<<EU_BLOCKS, 256, 0, stream>>>(
        ei, batch, ef0, nfa, nfb, efc, (const float*)(ws + OFF_GFD),
        ef_out, (float*)(ws + OFF_NACC), (u32*)(ws + OFF_NCNT),
        (float*)(ws + OFF_EMS), (u32*)(ws + OFF_EMCS));
    em_reduce_kernel<<<8, 256, 0, stream>>>(
        (const float*)(ws + OFF_EMS), (const u32*)(ws + OFF_EMCS),
        (float*)(ws + OFF_EMA), (float*)(ws + OFF_EMC));
    node_update_kernel<<<(NN + 63) / 64, 256, 0, stream>>>(
        nf0, nfn1, (const float*)(ws + OFF_NACC), (const u32*)(ws + OFF_NCNT),
        pk + 196608, (const float*)(ws + OFF_GFN3), batch,
        nf_out, (float*)(ws + OFF_NMA), (u32*)(ws + OFF_NMC));
    global_update_kernel<<<1, 256, 0, stream>>>(
        gf0, (const float*)(ws + OFF_GFP),
        (const float*)(ws + OFF_EMA), (const float*)(ws + OFF_EMC),
        (const float*)(ws + OFF_NMA), (const u32*)(ws + OFF_NMC),
        gmW, gmb, gf_out);
}

// Round 3
// 1006.760 us; speedup vs baseline: 1.1248x; 1.1248x over previous
//
#include <hip/hip_runtime.h>
#include <cstdio>

using u16 = unsigned short;
using u32 = unsigned int;

typedef __attribute__((ext_vector_type(8))) u16    u16x8;
typedef __attribute__((ext_vector_type(8))) __bf16 bf16x8;
typedef __attribute__((ext_vector_type(4))) float  f32x4;

constexpr int NN = 50000;   // nodes
constexpr int NE = 250000;  // edges
constexpr int EM_REP = 32;  // em replica count

// ---------------- ws layout (bytes) ----------------
constexpr size_t OFF_NFA  = 0;                                  // bf16 [NN,128]  nf_dense @ Wa
constexpr size_t OFF_NFB  = OFF_NFA  + (size_t)NN*128*2;        // bf16 [NN,128]  nf_dense @ Wb
constexpr size_t OFF_NFN1 = OFF_NFB  + (size_t)NN*128*2;        // bf16 [NN,128]  nf_dense @ Wn1
// ---- zeroed region start ----
constexpr size_t OFF_NACC = OFF_NFN1 + (size_t)NN*128*2;        // bf16 [NN,128] node accum (pk atomics)
constexpr size_t OFF_NCNT = OFF_NACC + (size_t)NN*128*2;        // u32  [NN] (padded to 200192B)
constexpr size_t OFF_ECNT = OFF_NCNT + 200192;                  // u32  [16] (padded 256)
constexpr size_t OFF_EM32 = OFF_ECNT + 256;                     // f32  [EM_REP,2048]
constexpr size_t OFF_NMA  = OFF_EM32 + (size_t)EM_REP*2048*4;   // f32  [2048]
constexpr size_t OFF_NMC  = OFF_NMA  + 8192;                    // u32  [16] (padded 256)
constexpr size_t ZERO_SZ  = (OFF_NMC + 256) - OFF_NACC;
// ---- zeroed region end ----
constexpr size_t OFF_GFP  = OFF_NMC  + 256;                     // f32  [16,128] gf_pre
constexpr size_t OFF_GFD  = OFF_GFP  + 8192;                    // f32  gf_pre@Wd+emb
constexpr size_t OFF_GFN3 = OFF_GFD  + 8192;                    // f32  gf_pre@Wn3+nmb
constexpr size_t OFF_PACK = OFF_GFN3 + 8192;                    // bf16 packed weights 212992
constexpr size_t WS_NEED  = OFF_PACK + (size_t)212992*2;

// ---------------- helpers ----------------
static __device__ __forceinline__ float b2f(u16 u) {
    union { u32 u; float f; } x; x.u = ((u32)u) << 16; return x.f;
}
static __device__ __forceinline__ u16 f2bf(float f) {
    union { float f; u32 u; } x; x.f = f;
    u32 r = x.u + 0x7fffu + ((x.u >> 16) & 1u);
    return (u16)(r >> 16);
}
static __device__ __forceinline__ float sp2(float x) {
    return fmaxf(x, 0.f) + __logf(1.f + __expf(-fabsf(x))) - 0.6931471805599453f;
}
static __device__ __forceinline__ bf16x8 ldbf8(const u16* p) {
    return __builtin_bit_cast(bf16x8, *(const u16x8*)p);
}

#if defined(__has_builtin)
#if __has_builtin(__builtin_amdgcn_global_atomic_fadd_v2bf16)
#define HAVE_PK_BF16 1
#endif
#endif

// packed bf16x2 atomic add into global bf16 buffer (addr 4B-aligned)
static __device__ __forceinline__ void atom_pk_bf16(u16* addr, float lo, float hi) {
#ifdef HAVE_PK_BF16
    typedef __attribute__((ext_vector_type(2))) short s16x2;
    s16x2 v; v.x = (short)f2bf(lo); v.y = (short)f2bf(hi);
    (void)__builtin_amdgcn_global_atomic_fadd_v2bf16(
        (__attribute__((address_space(1))) s16x2*)addr, v);
#else
    u32* p = (u32*)addr;
    u32 oldv = *p;
    while (true) {
        float flo = b2f((u16)(oldv & 0xffffu)) + lo;
        float fhi = b2f((u16)(oldv >> 16)) + hi;
        u32 newv = (u32)f2bf(flo) | ((u32)f2bf(fhi) << 16);
        u32 got = atomicCAS(p, oldv, newv);
        if (got == oldv) break;
        oldv = got;
    }
#endif
}

// ---------------- weight pre-swizzle (fp32 -> bf16 B-fragment order) ----------------
// packed[((nt*KC + kc)*64 + lane)*8 + j] = W[(rowOff + kc*32 + (lane>>4)*8 + j)*Nsrc + nt*16 + (lane&15)]
__global__ __launch_bounds__(256) void pack_kernel(
    const float* __restrict__ eW1, const float* __restrict__ eW2,
    const float* __restrict__ nW1, const float* __restrict__ nW2,
    const float* __restrict__ emW, const float* __restrict__ nmW,
    u16* __restrict__ dst)
{
    int gid = blockIdx.x * 256 + threadIdx.x;
    if (gid >= 212992) return;
    const float* src; int rowOff, Nsrc, KC, local;
    if      (gid <  32768) { src=eW1; rowOff=0;   Nsrc=256; KC=4; local=gid; }
    else if (gid <  65536) { src=eW2; rowOff=0;   Nsrc=128; KC=8; local=gid-32768; }
    else if (gid <  98304) { src=nW1; rowOff=0;   Nsrc=256; KC=4; local=gid-65536; }
    else if (gid < 131072) { src=nW2; rowOff=0;   Nsrc=128; KC=8; local=gid-98304; }
    else if (gid < 147456) { src=emW; rowOff=0;   Nsrc=128; KC=4; local=gid-131072; } // Wa
    else if (gid < 163840) { src=emW; rowOff=128; Nsrc=128; KC=4; local=gid-147456; } // Wb
    else if (gid < 180224) { src=emW; rowOff=256; Nsrc=128; KC=4; local=gid-163840; } // Wc
    else if (gid < 196608) { src=nmW; rowOff=0;   Nsrc=128; KC=4; local=gid-180224; } // Wn1
    else                   { src=nmW; rowOff=128; Nsrc=128; KC=4; local=gid-196608; } // Wn2
    int j    = local & 7;
    int lane = (local >> 3) & 63;
    int t    = local >> 9;
    int kc   = t & (KC - 1);
    int nt   = t >> (KC == 8 ? 3 : 2);
    int k = kc * 32 + ((lane >> 4) << 3) + j;
    int n = nt * 16 + (lane & 15);
    dst[gid] = f2bf(src[(size_t)(rowOff + k) * Nsrc + n]);
}

// ---------------- degree / per-graph directed-edge count ----------------
__global__ __launch_bounds__(256) void deg_kernel(
    const int* __restrict__ ei, const int* __restrict__ batch,
    u32* __restrict__ node_cnt, u32* __restrict__ ecnt)
{
    __shared__ u32 s_h[16];
    if (threadIdx.x < 16) s_h[threadIdx.x] = 0;
    __syncthreads();
    for (int e = blockIdx.x * 256 + threadIdx.x; e < NE; e += gridDim.x * 256) {
        int s = ei[e], d = ei[NE + e];
        atomicAdd(&node_cnt[d], 1u);
        atomicAdd(&node_cnt[s], 1u);
        atomicAdd(&s_h[batch[s]], 1u);
        atomicAdd(&s_h[batch[d]], 1u);
    }
    __syncthreads();
    if (threadIdx.x < 16 && s_h[threadIdx.x]) atomicAdd(&ecnt[threadIdx.x], s_h[threadIdx.x]);
}

// ---------------- node MLP: dense pre-block + 3 projections (Wa,Wb,Wn1) ----------------
__global__ __launch_bounds__(256) void mlp_node_kernel(
    const float* __restrict__ in,
    const u16* __restrict__ W1p, const float* __restrict__ b1,
    const u16* __restrict__ W2p, const float* __restrict__ b2,
    const u16* __restrict__ P0, const u16* __restrict__ P1, const u16* __restrict__ P2,
    u16* __restrict__ O0, u16* __restrict__ O1, u16* __restrict__ O2)
{
    __shared__ u16 sA[64 * 136];   // input tile, later h2 tile
    __shared__ u16 sH[64 * 264];   // h1 tile
    int tid  = threadIdx.x;
    int base = blockIdx.x * 64;
    {
        int r = tid >> 2, p = tid & 3;
        int row = base + r;
        u16* d = sA + r * 136 + p * 32;
        if (row < NN) {
            const float* s = in + (size_t)row * 128 + p * 32;
            #pragma unroll
            for (int i = 0; i < 4; i++) {
                f32x4 f0 = *(const f32x4*)(s + i * 8);
                f32x4 f1 = *(const f32x4*)(s + i * 8 + 4);
                u16x8 v;
                v[0]=f2bf(f0[0]); v[1]=f2bf(f0[1]); v[2]=f2bf(f0[2]); v[3]=f2bf(f0[3]);
                v[4]=f2bf(f1[0]); v[5]=f2bf(f1[1]); v[6]=f2bf(f1[2]); v[7]=f2bf(f1[3]);
                *(u16x8*)(d + i * 8) = v;
            }
        } else {
            u16x8 z = {0,0,0,0,0,0,0,0};
            #pragma unroll
            for (int i = 0; i < 4; i++) *(u16x8*)(d + i * 8) = z;
        }
    }
    __syncthreads();
    int lane = tid & 63, w = tid >> 6, q = lane >> 4, lm = lane & 15;
    // stage 1: nt-split across waves (weights read once per block)
    {
        bf16x8 a[4][4];
        #pragma unroll
        for (int rt = 0; rt < 4; rt++)
            #pragma unroll
            for (int kc = 0; kc < 4; kc++)
                a[rt][kc] = ldbf8(sA + (rt * 16 + lm) * 136 + kc * 32 + q * 8);
        for (int nti = 0; nti < 4; nti++) {
            int nt = w * 4 + nti;
            bf16x8 bfr[4];
            #pragma unroll
            for (int kc = 0; kc < 4; kc++) bfr[kc] = ldbf8(W1p + nt * 2048 + kc * 512 + lane * 8);
            f32x4 acc[4] = {{0,0,0,0},{0,0,0,0},{0,0,0,0},{0,0,0,0}};
            #pragma unroll
            for (int kc = 0; kc < 4; kc++)
                #pragma unroll
                for (int rt = 0; rt < 4; rt++)
                    acc[rt] = __builtin_amdgcn_mfma_f32_16x16x32_bf16(a[rt][kc], bfr[kc], acc[rt], 0, 0, 0);
            int col = nt * 16 + lm;
            float bias = b1[col];
            #pragma unroll
            for (int rt = 0; rt < 4; rt++)
                #pragma unroll
                for (int r = 0; r < 4; r++)
                    sH[(rt * 16 + q * 4 + r) * 264 + col] = f2bf(sp2(acc[rt][r] + bias));
        }
    }
    __syncthreads();
    // stage 2: row-split per wave
    {
        bf16x8 a[8];
        const u16* ar = sH + (w * 16 + lm) * 264;
        #pragma unroll
        for (int kc = 0; kc < 8; kc++) a[kc] = ldbf8(ar + kc * 32 + q * 8);
        for (int nt = 0; nt < 8; nt++) {
            f32x4 acc = {0.f, 0.f, 0.f, 0.f};
            const u16* bp = W2p + nt * 4096 + lane * 8;
            #pragma unroll
            for (int kc = 0; kc < 8; kc++)
                acc = __builtin_amdgcn_mfma_f32_16x16x32_bf16(a[kc], ldbf8(bp + kc * 512), acc, 0, 0, 0);
            int col = nt * 16 + lm;
            float bias = b2[col];
            #pragma unroll
            for (int r = 0; r < 4; r++)
                sA[(w * 16 + q * 4 + r) * 136 + col] = f2bf(sp2(acc[r] + bias));
        }
    }
    // stage 3: three projections, row-split
    {
        bf16x8 a[4];
        const u16* ar = sA + (w * 16 + lm) * 136;
        #pragma unroll
        for (int kc = 0; kc < 4; kc++) a[kc] = ldbf8(ar + kc * 32 + q * 8);
        const u16* Ps[3] = {P0, P1, P2};
        u16*       Os[3] = {O0, O1, O2};
        #pragma unroll
        for (int p = 0; p < 3; p++) {
            for (int nt = 0; nt < 8; nt++) {
                f32x4 acc = {0.f, 0.f, 0.f, 0.f};
                const u16* bp = Ps[p] + nt * 2048 + lane * 8;
                #pragma unroll
                for (int kc = 0; kc < 4; kc++)
                    acc = __builtin_amdgcn_mfma_f32_16x16x32_bf16(a[kc], ldbf8(bp + kc * 512), acc, 0, 0, 0);
                int col = nt * 16 + lm;
                #pragma unroll
                for (int r = 0; r < 4; r++) {
                    int row = base + w * 16 + q * 4 + r;
                    if (row < NN) Os[p][(size_t)row * 128 + col] = f2bf(acc[r]);
                }
            }
        }
    }
}

// ---------------- global-features pre-block (16 blocks, coalesced) ----------------
__global__ __launch_bounds__(256) void gdense_kernel(
    const float* __restrict__ gf0, const float* __restrict__ gW1, const float* __restrict__ gb1,
    const float* __restrict__ gW2, const float* __restrict__ gb2,
    const float* __restrict__ emW, const float* __restrict__ emb,
    const float* __restrict__ nmW, const float* __restrict__ nmb,
    float* __restrict__ gf_pre, float* __restrict__ gfd, float* __restrict__ gfn3b)
{
    __shared__ float s_in[128], s_h1[256], s_h2[128];
    int r = blockIdx.x;  // graph row 0..15
    int t = threadIdx.x;
    if (t < 128) s_in[t] = gf0[r * 128 + t];
    __syncthreads();
    {
        float acc = gb1[t];
        for (int k = 0; k < 128; k++) acc += s_in[k] * gW1[k * 256 + t];
        s_h1[t] = sp2(acc);
    }
    __syncthreads();
    if (t < 128) {
        float acc = gb2[t];
        for (int k = 0; k < 256; k++) acc += s_h1[k] * gW2[k * 128 + t];
        float v = sp2(acc);
        s_h2[t] = v; gf_pre[r * 128 + t] = v;
    }
    __syncthreads();
    if (t < 128) {
        float a1 = emb[t];
        for (int k = 0; k < 128; k++) a1 += s_h2[k] * emW[(size_t)(384 + k) * 128 + t];
        gfd[r * 128 + t] = a1;
    } else {
        int c = t - 128;
        float a2 = nmb[c];
        for (int k = 0; k < 128; k++) a2 += s_h2[k] * nmW[(size_t)(256 + k) * 128 + c];
        gfn3b[r * 128 + c] = a2;
    }
}

// ---------------- fused edge kernel: MLP + edge update + scatters ----------------
__global__ __launch_bounds__(256) void edge_fused_kernel(
    const float* __restrict__ ef0, const int* __restrict__ ei, const int* __restrict__ batch,
    const u16* __restrict__ W1p, const float* __restrict__ b1,
    const u16* __restrict__ W2p, const float* __restrict__ b2,
    const u16* __restrict__ Wcp,
    const u16* __restrict__ nfa, const u16* __restrict__ nfb, const float* __restrict__ gfd,
    float* __restrict__ ef_out, u16* __restrict__ node_acc, float* __restrict__ em32)
{
    __shared__ u16 sA[64 * 136];    // ef0 tile (bf16), later h2
    __shared__ u16 sH[64 * 264];    // h1
    __shared__ u16 sEC[64 * 136];   // ec = h2 @ Wc
    __shared__ float s_em[2048];
    __shared__ int s_s[64], s_d[64], s_bs[64], s_bd[64];
    int tid  = threadIdx.x;
    int base = blockIdx.x * 64;
    for (int i = tid; i < 2048; i += 256) s_em[i] = 0.f;
    if (tid < 64)       { int e = base + tid;      s_s[tid]      = (e < NE) ? ei[e]      : 0; }
    else if (tid < 128) { int e = base + tid - 64; s_d[tid - 64] = (e < NE) ? ei[NE + e] : 0; }
    // stage ef0 tile -> bf16
    {
        int r = tid >> 2, p = tid & 3;
        int row = base + r;
        u16* d = sA + r * 136 + p * 32;
        if (row < NE) {
            const float* s = ef0 + (size_t)row * 128 + p * 32;
            #pragma unroll
            for (int i = 0; i < 4; i++) {
                f32x4 f0 = *(const f32x4*)(s + i * 8);
                f32x4 f1 = *(const f32x4*)(s + i * 8 + 4);
                u16x8 v;
                v[0]=f2bf(f0[0]); v[1]=f2bf(f0[1]); v[2]=f2bf(f0[2]); v[3]=f2bf(f0[3]);
                v[4]=f2bf(f1[0]); v[5]=f2bf(f1[1]); v[6]=f2bf(f1[2]); v[7]=f2bf(f1[3]);
                *(u16x8*)(d + i * 8) = v;
            }
        } else {
            u16x8 z = {0,0,0,0,0,0,0,0};
            #pragma unroll
            for (int i = 0; i < 4; i++) *(u16x8*)(d + i * 8) = z;
        }
    }
    __syncthreads();
    if (tid < 64)       s_bs[tid]      = batch[s_s[tid]];
    else if (tid < 128) s_bd[tid - 64] = batch[s_d[tid - 64]];
    int lane = tid & 63, w = tid >> 6, q = lane >> 4, lm = lane & 15;
    // stage 1: nt-split
    {
        bf16x8 a[4][4];
        #pragma unroll
        for (int rt = 0; rt < 4; rt++)
            #pragma unroll
            for (int kc = 0; kc < 4; kc++)
                a[rt][kc] = ldbf8(sA + (rt * 16 + lm) * 136 + kc * 32 + q * 8);
        for (int nti = 0; nti < 4; nti++) {
            int nt = w * 4 + nti;
            bf16x8 bfr[4];
            #pragma unroll
            for (int kc = 0; kc < 4; kc++) bfr[kc] = ldbf8(W1p + nt * 2048 + kc * 512 + lane * 8);
            f32x4 acc[4] = {{0,0,0,0},{0,0,0,0},{0,0,0,0},{0,0,0,0}};
            #pragma unroll
            for (int kc = 0; kc < 4; kc++)
                #pragma unroll
                for (int rt = 0; rt < 4; rt++)
                    acc[rt] = __builtin_amdgcn_mfma_f32_16x16x32_bf16(a[rt][kc], bfr[kc], acc[rt], 0, 0, 0);
            int col = nt * 16 + lm;
            float bias = b1[col];
            #pragma unroll
            for (int rt = 0; rt < 4; rt++)
                #pragma unroll
                for (int r = 0; r < 4; r++)
                    sH[(rt * 16 + q * 4 + r) * 264 + col] = f2bf(sp2(acc[rt][r] + bias));
        }
    }
    __syncthreads();
    // stage 2: row-split, h2 -> sA (wave-private rows)
    {
        bf16x8 a[8];
        const u16* ar = sH + (w * 16 + lm) * 264;
        #pragma unroll
        for (int kc = 0; kc < 8; kc++) a[kc] = ldbf8(ar + kc * 32 + q * 8);
        for (int nt = 0; nt < 8; nt++) {
            f32x4 acc = {0.f, 0.f, 0.f, 0.f};
            const u16* bp = W2p + nt * 4096 + lane * 8;
            #pragma unroll
            for (int kc = 0; kc < 8; kc++)
                acc = __builtin_amdgcn_mfma_f32_16x16x32_bf16(a[kc], ldbf8(bp + kc * 512), acc, 0, 0, 0);
            int col = nt * 16 + lm;
            float bias = b2[col];
            #pragma unroll
            for (int r = 0; r < 4; r++)
                sA[(w * 16 + q * 4 + r) * 136 + col] = f2bf(sp2(acc[r] + bias));
        }
    }
    // stage 3: ec = h2 @ Wc -> sEC (wave-private rows, same-wave LDS ordering)
    {
        bf16x8 a[4];
        const u16* ar = sA + (w * 16 + lm) * 136;
        #pragma unroll
        for (int kc = 0; kc < 4; kc++) a[kc] = ldbf8(ar + kc * 32 + q * 8);
        for (int nt = 0; nt < 8; nt++) {
            f32x4 acc = {0.f, 0.f, 0.f, 0.f};
            const u16* bp = Wcp + nt * 2048 + lane * 8;
            #pragma unroll
            for (int kc = 0; kc < 4; kc++)
                acc = __builtin_amdgcn_mfma_f32_16x16x32_bf16(a[kc], ldbf8(bp + kc * 512), acc, 0, 0, 0);
            int col = nt * 16 + lm;
            #pragma unroll
            for (int r = 0; r < 4; r++)
                sEC[(w * 16 + q * 4 + r) * 136 + col] = f2bf(acc[r]);
        }
    }
    __syncthreads();
    // scatter phase: 1024 slices (64 edges x 16 col-groups of 8), 4 per thread
    {
        int el0 = tid >> 4, ci = (tid & 15) * 8;
        for (int k = 0; k < 4; k++) {
            int el = el0 + 16 * k;
            int e  = base + el;
            if (e >= NE) break;
            int s = s_s[el], d = s_d[el], gbf = s_bs[el], gbb = s_bd[el];
            u16x8 va  = *(const u16x8*)(nfa + (size_t)s * 128 + ci);
            u16x8 vbd = *(const u16x8*)(nfb + (size_t)d * 128 + ci);
            u16x8 vad = *(const u16x8*)(nfa + (size_t)d * 128 + ci);
            u16x8 vbs = *(const u16x8*)(nfb + (size_t)s * 128 + ci);
            u16x8 ecv = *(const u16x8*)(sEC + el * 136 + ci);
            const float* gff = gfd + gbf * 128 + ci;
            const float* gfb = gfd + gbb * 128 + ci;
            const float* e0p = ef0 + (size_t)e * 128 + ci;
            float* eop = ef_out + (size_t)e * 128 + ci;
            float f[8], g[8];
            #pragma unroll
            for (int i = 0; i < 8; i++) {
                float ec = b2f(ecv[i]);
                f[i] = b2f(va[i])  + b2f(vbd[i]) + ec + gff[i];
                g[i] = b2f(vad[i]) + b2f(vbs[i]) + ec + gfb[i];
                eop[i] = 0.5f * (f[i] + g[i]) + e0p[i];
            }
            #pragma unroll
            for (int i = 0; i < 8; i++) {
                atomicAdd(&s_em[gbf * 128 + ci + i], f[i]);
                atomicAdd(&s_em[gbb * 128 + ci + i], g[i]);
            }
            u16* nd = node_acc + (size_t)d * 128 + ci;
            u16* ns = node_acc + (size_t)s * 128 + ci;
            #pragma unroll
            for (int i = 0; i < 4; i++) {
                atom_pk_bf16(nd + 2 * i, f[2 * i], f[2 * i + 1]);
                atom_pk_bf16(ns + 2 * i, g[2 * i], g[2 * i + 1]);
            }
        }
    }
    __syncthreads();
    float* dstm = em32 + (size_t)(blockIdx.x & (EM_REP - 1)) * 2048;
    for (int i = tid; i < 2048; i += 256) unsafeAtomicAdd(&dstm[i], s_em[i]);
}

// ---------------- node update (efm @ Wn2 via MFMA) ----------------
__global__ __launch_bounds__(256) void node_update_kernel(
    const float* __restrict__ nf0, const u16* __restrict__ nfn1,
    const u16* __restrict__ node_acc, const u32* __restrict__ node_cnt,
    const u16* __restrict__ Wn2p, const float* __restrict__ gfn3b, const int* __restrict__ batch,
    float* __restrict__ nf_out, float* __restrict__ nm_acc, u32* __restrict__ nm_cnt)
{
    __shared__ u16 sE[64 * 136];
    __shared__ float s_nm[2048];
    __shared__ u32 s_ncnt[16];
    int tid = threadIdx.x;
    for (int i = tid; i < 2048; i += 256) s_nm[i] = 0.f;
    if (tid < 16) s_ncnt[tid] = 0;
    __syncthreads();
    int base = blockIdx.x * 64;
    {
        int r = tid >> 2, p = tid & 3;
        int n = base + r;
        u16* d = sE + r * 136 + p * 32;
        if (n < NN) {
            float inv = 1.f / fmaxf((float)node_cnt[n], 1.f);
            const u16* pa = node_acc + (size_t)n * 128 + p * 32;
            #pragma unroll
            for (int i = 0; i < 4; i++) {
                u16x8 v = *(const u16x8*)(pa + i * 8);
                u16x8 o;
                #pragma unroll
                for (int j = 0; j < 8; j++) o[j] = f2bf(b2f(v[j]) * inv);
                *(u16x8*)(d + i * 8) = o;
            }
            if (p == 0) atomicAdd(&s_ncnt[batch[n]], 1u);
        } else {
            u16x8 z = {0,0,0,0,0,0,0,0};
            #pragma unroll
            for (int i = 0; i < 4; i++) *(u16x8*)(d + i * 8) = z;
        }
    }
    __syncthreads();
    int lane = tid & 63, w = tid >> 6, q = lane >> 4, lm = lane & 15;
    int rows[4]; bool ok[4]; int gg[4];
    #pragma unroll
    for (int r = 0; r < 4; r++) {
        rows[r] = base + w * 16 + q * 4 + r;
        ok[r] = rows[r] < NN;
        gg[r] = ok[r] ? batch[rows[r]] : 0;
    }
    bf16x8 a[4];
    const u16* ar = sE + (w * 16 + lm) * 136;
    #pragma unroll
    for (int kc = 0; kc < 4; kc++) a[kc] = ldbf8(ar + kc * 32 + q * 8);
    for (int nt = 0; nt < 8; nt++) {
        f32x4 acc = {0.f, 0.f, 0.f, 0.f};
        const u16* bp = Wn2p + nt * 2048 + lane * 8;
        #pragma unroll
        for (int kc = 0; kc < 4; kc++)
            acc = __builtin_amdgcn_mfma_f32_16x16x32_bf16(a[kc], ldbf8(bp + kc * 512), acc, 0, 0, 0);
        int col = nt * 16 + lm;
        #pragma unroll
        for (int r = 0; r < 4; r++) {
            if (ok[r]) {
                size_t idx = (size_t)rows[r] * 128 + col;
                float upd = acc[r] + b2f(nfn1[idx]) + gfn3b[gg[r] * 128 + col];
                nf_out[idx] = upd + nf0[idx];
                atomicAdd(&s_nm[gg[r] * 128 + col], upd);
            }
        }
    }
    __syncthreads();
    for (int g = 0; g < 16; g++) {
        u32 c = s_ncnt[g];
        if (c) {
            if (tid < 128) unsafeAtomicAdd(&nm_acc[g * 128 + tid], s_nm[g * 128 + tid]);
            if (tid == 0) atomicAdd(&nm_cnt[g], c);
        }
    }
}

// ---------------- global update (tiny, 1 block) ----------------
__global__ __launch_bounds__(256) void global_update_kernel(
    const float* __restrict__ gf0, const float* __restrict__ gf_pre,
    const float* __restrict__ em32, const u32* __restrict__ ecnt,
    const float* __restrict__ nm_acc, const u32* __restrict__ nm_cnt,
    const float* __restrict__ gmW, const float* __restrict__ gmb,
    float* __restrict__ gf_out)
{
    __shared__ float s_cat[16 * 384];
    int tid = threadIdx.x;
    for (int i = tid; i < 2048; i += 256) {
        int g = i >> 7, c = i & 127;
        float s = 0.f;
        for (int r = 0; r < EM_REP; r++) s += em32[(size_t)r * 2048 + i];
        s_cat[g * 384 + c]       = s / fmaxf((float)ecnt[g], 1.f);
        s_cat[g * 384 + 128 + c] = nm_acc[i] / fmaxf((float)nm_cnt[g], 1.f);
        s_cat[g * 384 + 256 + c] = gf_pre[i];
    }
    __syncthreads();
    for (int o = tid; o < 2048; o += 256) {
        int g = o >> 7, c = o & 127;
        float acc = gmb[c];
        for (int k = 0; k < 384; k++) acc += s_cat[g * 384 + k] * gmW[k * 128 + c];
        gf_out[o] = acc + gf0[o];
    }
}

// ---------------- launcher ----------------
extern "C" void kernel_launch(void* const* d_in, const int* in_sizes, int n_in,
                              void* d_out, int out_size, void* d_ws, size_t ws_size,
                              hipStream_t stream) {
    const float* nf0 = (const float*)d_in[0];
    const int*   ei  = (const int*)d_in[1];
    const float* ef0 = (const float*)d_in[2];
    const float* gf0 = (const float*)d_in[3];
    const int* batch = (const int*)d_in[4];
    const float *eW1 = (const float*)d_in[5],  *eb1 = (const float*)d_in[6];
    const float *eW2 = (const float*)d_in[7],  *eb2 = (const float*)d_in[8];
    const float *nW1 = (const float*)d_in[9],  *nb1 = (const float*)d_in[10];
    const float *nW2 = (const float*)d_in[11], *nb2 = (const float*)d_in[12];
    const float *gW1 = (const float*)d_in[13], *gb1 = (const float*)d_in[14];
    const float *gW2 = (const float*)d_in[15], *gb2 = (const float*)d_in[16];
    const float *emW = (const float*)d_in[17], *emb = (const float*)d_in[18];
    const float *nmW = (const float*)d_in[19], *nmb = (const float*)d_in[20];
    const float *gmW = (const float*)d_in[21], *gmb = (const float*)d_in[22];

    if (ws_size < WS_NEED) {
        fprintf(stderr, "kernel_launch: ws too small: %zu < %zu\n", ws_size, WS_NEED);
        return;
    }
    char* ws = (char*)d_ws;
    u16* nfa  = (u16*)(ws + OFF_NFA);
    u16* nfb  = (u16*)(ws + OFF_NFB);
    u16* nfn1 = (u16*)(ws + OFF_NFN1);
    u16* nacc = (u16*)(ws + OFF_NACC);
    u32* ncnt = (u32*)(ws + OFF_NCNT);
    u32* ecnt = (u32*)(ws + OFF_ECNT);
    float* em32 = (float*)(ws + OFF_EM32);
    u16* pk   = (u16*)(ws + OFF_PACK);

    float* nf_out = (float*)d_out;
    float* ef_out = nf_out + (size_t)NN * 128;
    float* gf_out = ef_out + (size_t)NE * 128;

    hipMemsetAsync(ws + OFF_NACC, 0, ZERO_SZ, stream);

    pack_kernel<<<832, 256, 0, stream>>>(eW1, eW2, nW1, nW2, emW, nmW, pk);
    gdense_kernel<<<16, 256, 0, stream>>>(gf0, gW1, gb1, gW2, gb2, emW, emb, nmW, nmb,
                                          (float*)(ws + OFF_GFP), (float*)(ws + OFF_GFD),
                                          (float*)(ws + OFF_GFN3));
    deg_kernel<<<512, 256, 0, stream>>>(ei, batch, ncnt, ecnt);
    mlp_node_kernel<<<(NN + 63) / 64, 256, 0, stream>>>(
        nf0, pk + 65536, nb1, pk + 98304, nb2,
        pk + 131072, pk + 147456, pk + 180224, nfa, nfb, nfn1);
    edge_fused_kernel<<<(NE + 63) / 64, 256, 0, stream>>>(
        ef0, ei, batch, pk + 0, eb1, pk + 32768, eb2, pk + 163840,
        nfa, nfb, (const float*)(ws + OFF_GFD),
        ef_out, nacc, em32);
    node_update_kernel<<<(NN + 63) / 64, 256, 0, stream>>>(
        nf0, nfn1, nacc, ncnt,
        pk + 196608, (const float*)(ws + OFF_GFN3), batch,
        nf_out, (float*)(ws + OFF_NMA), (u32*)(ws + OFF_NMC));
    global_update_kernel<<<1, 256, 0, stream>>>(
        gf0, (const float*)(ws + OFF_GFP),
        em32, ecnt,
        (const float*)(ws + OFF_NMA), (const u32*)(ws + OFF_NMC),
        gmW, gmb, gf_out);
}